// Round 7
// baseline (91.766 us; speedup 1.0000x reference)
//
#include <hip/hip_runtime.h>
#include <hip/hip_bf16.h>
#include <math.h>

#define NTOK 8192
#define DIN  4096
#define HG   256
#define NE   64
#define SPLITK 4
#define KSTEPS 32          // ksteps of 32 per split (4096/4/32)
#define TR   16            // rows per tail block

typedef __attribute__((ext_vector_type(8))) short short8;
typedef __attribute__((ext_vector_type(4))) short short4v;
typedef __attribute__((ext_vector_type(4))) float f32x4;

__device__ __forceinline__ unsigned short f2bf_rne(float f) {
    union { float f; unsigned int u; } v; v.f = f;
    unsigned int r = v.u + 0x7fffu + ((v.u >> 16) & 1u);
    return (unsigned short)(r >> 16);
}
__device__ __forceinline__ float bf2f(unsigned short b) {
    union { unsigned int u; float f; } v; v.u = ((unsigned int)b) << 16;
    return v.f;
}

typedef const __attribute__((address_space(1))) unsigned int* gptr_t;
typedef __attribute__((address_space(3))) unsigned int* lptr_t;
__device__ __forceinline__ void gload_lds16(const void* g, void* l) {
    __builtin_amdgcn_global_load_lds((gptr_t)g, (lptr_t)l, 16, 0, 0);
}

// ---------------------------------------------------------------------------
// Pre-convert w1 [HG][DIN] fp32 -> fragment-ordered bf16 hi/lo tiles.
// w1t[kstep][c][lane][j]: c = hl*16+unit; value = (hi|lo) of
// w1[unit*16 + (lane&15)][kstep*32 + (lane>>4)*8 + j].   (validated r3-r6)
// ---------------------------------------------------------------------------
__global__ __launch_bounds__(512) void convert_w1_kernel(
    const float* __restrict__ w1, unsigned short* __restrict__ w1t)
{
    const int id    = blockIdx.x * 512 + threadIdx.x;
    const int lane  = id & 63;
    const int cg    = id >> 6;           // 0..4095
    const int kstep = cg >> 5;
    const int c     = cg & 31;
    const int hl    = c >> 4;
    const int unit  = c & 15;
    const int n     = unit * 16 + (lane & 15);
    const int k     = kstep * 32 + ((lane >> 4) & 3) * 8;

    const float* src = w1 + (size_t)n * DIN + k;
    short8 v;
#pragma unroll
    for (int j = 0; j < 8; ++j) {
        float f = src[j];
        unsigned short hi = f2bf_rne(f);
        v[j] = (hl == 0) ? (short)hi : (short)f2bf_rne(f - bf2f(hi));
    }
    *(short8*)(w1t + (size_t)cg * 512 + lane * 8) = v;
}

// ---------------------------------------------------------------------------
// GEMM1 (split-K): P[s][NTOK][HG] = x(bf16x3) @ w1^T for k-range s.
// 512 blocks = 128 m-tiles (BM=64) x 4 splitK; 256 thr = 4 waves, each wave
// owns a 64x64 quadrant (4 m-frag x 4 n-frag -> 48 MFMA : 16 ds_read = 3:1).
// As double-buffered (16 KB) + Bs double (64 KB) = 80 KB -> 2 blocks/CU.
// ONE barrier per kstep; loads for tt+1 issued at top of tt (full-body
// latency window ~1900 cyc > HBM latency).
// ---------------------------------------------------------------------------
__global__ __launch_bounds__(256, 2) void gemm1_mfma_kernel(
    const float* __restrict__ x, const unsigned short* __restrict__ w1t,
    float* __restrict__ P)
{
    __shared__ unsigned short As[2][2][4][512];   // [buf][hl][unit][slot*8+j] 16 KB
    __shared__ unsigned short Bs[2][2][16][512];  // [buf][hl][unit][...]     64 KB

    const int bid  = blockIdx.x;
    const int mblk = bid & 127;
    const int s    = bid >> 7;
    const int t    = threadIdx.x;
    const int lane = t & 63;
    const int w    = t >> 6;          // wave = n-quadrant 0..3

    const int m_base = mblk * 64;
    const int kstep0 = s * KSTEPS;

    // A staging: thread t -> unit = t>>6, q = t&63 -> row = unit*16+(q&15),
    // k-segment = (q>>4)*8 (8 contiguous floats). LDS dest slot q -> per-wave
    // lane-contiguous b128 writes (conflict-free; layout validated r3-r6).
    const int a_unit = t >> 6;
    const int a_q    = t & 63;
    const int a_row  = a_unit * 16 + (a_q & 15);
    const int a_koff = (a_q >> 4) * 8;
    const float* asrc = x + (size_t)(m_base + a_row) * DIN
                          + (size_t)kstep0 * 32 + a_koff;
    const int a_ldso = a_q * 8;       // shorts within As[buf][hl][unit]

    f32x4 acc[4][4];
#pragma unroll
    for (int i = 0; i < 4; ++i)
#pragma unroll
        for (int j = 0; j < 4; ++j) acc[i][j] = (f32x4)0.f;

#define CVT8_STORE(BUF, F0, F1)                                               \
    {   short8 vh_, vl_;                                                      \
        float ff_[8] = { (F0).x, (F0).y, (F0).z, (F0).w,                      \
                         (F1).x, (F1).y, (F1).z, (F1).w };                    \
        _Pragma("unroll")                                                     \
        for (int j_ = 0; j_ < 8; ++j_) {                                      \
            unsigned short h_ = f2bf_rne(ff_[j_]);                            \
            vh_[j_] = (short)h_;                                              \
            vl_[j_] = (short)f2bf_rne(ff_[j_] - bf2f(h_));                    \
        }                                                                     \
        *(short8*)&As[BUF][0][a_unit][a_ldso] = vh_;                          \
        *(short8*)&As[BUF][1][a_unit][a_ldso] = vl_;                          \
    }

    // ---- prologue: issue B0 gloads (8 per wave), load+convert A0 ----
#pragma unroll
    for (int i = 0; i < 8; ++i) {
        const int c = w * 8 + i;
        gload_lds16(w1t + ((size_t)kstep0 * 32 + c) * 512 + lane * 8,
                    &Bs[0][c >> 4][c & 15][0]);
    }
    {
        float4 a0 = *(const float4*)(asrc);
        float4 a1 = *(const float4*)(asrc + 4);
        CVT8_STORE(0, a0, a1)
    }
    __syncthreads();

    // ---- main loop: ONE barrier per kstep ----
#pragma unroll 1
    for (int tt = 0; tt < KSTEPS; ++tt) {
        const int bcur = tt & 1, bnxt = bcur ^ 1;
        const bool last = (tt == KSTEPS - 1);

        // issue next-tile loads first: in flight across the whole body
        float4 nx0, nx1;
        if (!last) {
            const float* ap = asrc + (size_t)(tt + 1) * 32;
            nx0 = *(const float4*)(ap);
            nx1 = *(const float4*)(ap + 4);
#pragma unroll
            for (int i = 0; i < 8; ++i) {
                const int c = w * 8 + i;
                gload_lds16(w1t + ((size_t)(kstep0 + tt + 1) * 32 + c) * 512 + lane * 8,
                            &Bs[bnxt][c >> 4][c & 15][0]);
            }
        }

        // fragments (lane*16B contiguous -> conflict-free)
        short8 ahf[4], alf[4], bhf[4], blf[4];
#pragma unroll
        for (int mr = 0; mr < 4; ++mr) {
            ahf[mr] = *(const short8*)&As[bcur][0][mr][lane * 8];
            alf[mr] = *(const short8*)&As[bcur][1][mr][lane * 8];
        }
#pragma unroll
        for (int nr = 0; nr < 4; ++nr) {
            bhf[nr] = *(const short8*)&Bs[bcur][0][w * 4 + nr][lane * 8];
            blf[nr] = *(const short8*)&Bs[bcur][1][w * 4 + nr][lane * 8];
        }

        // bf16x3: Ah*Bh + Ah*Bl + Al*Bh   (48 MFMA)
#pragma unroll
        for (int mr = 0; mr < 4; ++mr)
#pragma unroll
            for (int nr = 0; nr < 4; ++nr)
                acc[mr][nr] = __builtin_amdgcn_mfma_f32_16x16x32_bf16(
                    ahf[mr], bhf[nr], acc[mr][nr], 0, 0, 0);
#pragma unroll
        for (int mr = 0; mr < 4; ++mr)
#pragma unroll
            for (int nr = 0; nr < 4; ++nr)
                acc[mr][nr] = __builtin_amdgcn_mfma_f32_16x16x32_bf16(
                    ahf[mr], blf[nr], acc[mr][nr], 0, 0, 0);
#pragma unroll
        for (int mr = 0; mr < 4; ++mr)
#pragma unroll
            for (int nr = 0; nr < 4; ++nr)
                acc[mr][nr] = __builtin_amdgcn_mfma_f32_16x16x32_bf16(
                    alf[mr], bhf[nr], acc[mr][nr], 0, 0, 0);

        if (!last) {
            CVT8_STORE(bnxt, nx0, nx1)   // write-late into the other As buf
            __syncthreads();             // drains this kstep's gloads + ds_writes
        }
    }
#undef CVT8_STORE

    // ---- epilogue: store fp32 partial (mapping validated r3-r6) ----
    float* pb = P + (size_t)s * ((size_t)NTOK * HG);
#pragma unroll
    for (int mr = 0; mr < 4; ++mr)
#pragma unroll
        for (int nr = 0; nr < 4; ++nr) {
            const int n = w * 64 + nr * 16 + (lane & 15);
#pragma unroll
            for (int r = 0; r < 4; ++r) {
                const int m = m_base + mr * 16 + ((lane >> 4) & 3) * 4 + r;
                pb[(size_t)m * HG + n] = acc[mr][nr][r];
            }
        }
}

// ---------------------------------------------------------------------------
// Fused tail: 512 blocks x 512 thr, TR=16 rows/block, 25 KB LDS ->
// 2 blocks/CU. (unchanged from round 6 -- validated, ~4 us)
// d_out = [ indices(float) N*2 | gates N*2 | probs N*64 ]
// ---------------------------------------------------------------------------
__global__ __launch_bounds__(512, 4) void reduce_gate_kernel(
    const float* __restrict__ P, const float* __restrict__ b1,
    const float* __restrict__ w2, float* __restrict__ out)
{
    __shared__ float h_lds[TR][260];
    __shared__ float lg[NE][33];

    const int t    = threadIdx.x;
    const int lane = t & 63;
    const int w    = t >> 6;
    const int r0   = blockIdx.x * TR;
    const size_t SS = (size_t)NTOK * HG;

    // ---- phase 1: reduce + bias + gelu (coalesced: 32 thr = one row) ----
    {
        const int row = t >> 5;          // 0..15
        const int sg  = t & 31;          // 8 floats at cols sg*8
        const size_t base = (size_t)(r0 + row) * HG + sg * 8;

        float q[8];
#pragma unroll
        for (int half = 0; half < 2; ++half) {
            float4 v0 = *(const float4*)(P + base + half * 4);
            float4 v1 = *(const float4*)(P + base + SS + half * 4);
            float4 v2 = *(const float4*)(P + base + 2 * SS + half * 4);
            float4 v3 = *(const float4*)(P + base + 3 * SS + half * 4);
            float4 bb = *(const float4*)(b1 + sg * 8 + half * 4);
            q[half * 4 + 0] = v0.x + v1.x + v2.x + v3.x + bb.x;
            q[half * 4 + 1] = v0.y + v1.y + v2.y + v3.y + bb.y;
            q[half * 4 + 2] = v0.z + v1.z + v2.z + v3.z + bb.z;
            q[half * 4 + 3] = v0.w + v1.w + v2.w + v3.w + bb.w;
        }
#pragma unroll
        for (int c = 0; c < 8; ++c)
            q[c] = 0.5f * q[c] * (1.0f + erff(q[c] * 0.70710678118654752440f));

        *(float4*)&h_lds[row][sg * 8]     = make_float4(q[0], q[1], q[2], q[3]);
        *(float4*)&h_lds[row][sg * 8 + 4] = make_float4(q[4], q[5], q[6], q[7]);
    }
    __syncthreads();

    // ---- phase 2: logits; wave w -> 8 experts, quarter-K per lane ----
    const int e0   = w * 8;
    const int rowp = lane & 15;
    const int kq   = lane >> 4;          // 0..3 -> k-range kq*64

    float acc[8];
#pragma unroll
    for (int i = 0; i < 8; ++i) acc[i] = 0.f;

    const float* w2b = w2 + (size_t)e0 * HG + kq * 64;
#pragma unroll 1
    for (int kc = 0; kc < 64; kc += 8) {
        float a[8];
        *(float4*)&a[0] = *(const float4*)&h_lds[rowp][kq * 64 + kc];
        *(float4*)&a[4] = *(const float4*)&h_lds[rowp][kq * 64 + kc + 4];
#pragma unroll
        for (int n = 0; n < 8; ++n) {
            const float* wr = w2b + (size_t)n * HG + kc;
            float4 w0 = *(const float4*)(wr);
            float4 w1v = *(const float4*)(wr + 4);
            acc[n] = fmaf(w0.x, a[0], acc[n]);
            acc[n] = fmaf(w0.y, a[1], acc[n]);
            acc[n] = fmaf(w0.z, a[2], acc[n]);
            acc[n] = fmaf(w0.w, a[3], acc[n]);
            acc[n] = fmaf(w1v.x, a[4], acc[n]);
            acc[n] = fmaf(w1v.y, a[5], acc[n]);
            acc[n] = fmaf(w1v.z, a[6], acc[n]);
            acc[n] = fmaf(w1v.w, a[7], acc[n]);
        }
    }
#pragma unroll
    for (int n = 0; n < 8; ++n) {
        acc[n] += __shfl_xor(acc[n], 16);
        acc[n] += __shfl_xor(acc[n], 32);
    }
    if (lane < 16) {
#pragma unroll
        for (int n = 0; n < 8; ++n) lg[e0 + n][rowp] = acc[n];
    }
    __syncthreads();

    // ---- phase 3: softmax + stable top-2 (threads 0..15) ----
    if (t < TR) {
        float l[NE];
#pragma unroll
        for (int e = 0; e < NE; ++e) l[e] = lg[e][t];

        float mx = l[0];
#pragma unroll
        for (int e = 1; e < NE; ++e) mx = fmaxf(mx, l[e]);

        float ssum = 0.f;
#pragma unroll
        for (int e = 0; e < NE; ++e) { float p = expf(l[e] - mx); l[e] = p; ssum += p; }
        const float inv = 1.0f / ssum;
#pragma unroll
        for (int e = 0; e < NE; ++e) l[e] *= inv;

        float v1 = -1.0f, v2 = -2.0f;
        int   i1 = 0,     i2 = 0;
#pragma unroll
        for (int e = 0; e < NE; ++e) {
            const float p  = l[e];
            const bool  g1 = p > v1;
            const bool  g2 = p > v2;
            const float nv2 = g1 ? v1 : (g2 ? p : v2);
            const int   ni2 = g1 ? i1 : (g2 ? e : i2);
            v1 = g1 ? p : v1;
            i1 = g1 ? e : i1;
            v2 = nv2;
            i2 = ni2;
        }

        const int row = r0 + t;
        float* out_idx  = out;
        float* out_gate = out + 2 * NTOK;
        float* out_prob = out + 4 * NTOK;
        out_idx[2 * row + 0]  = (float)i1;
        out_idx[2 * row + 1]  = (float)i2;
        out_gate[2 * row + 0] = v1;
        out_gate[2 * row + 1] = v2;

        float* pr = out_prob + (size_t)row * NE;
#pragma unroll
        for (int e = 0; e < NE; e += 4)
            *(float4*)(pr + e) = make_float4(l[e], l[e + 1], l[e + 2], l[e + 3]);
    }
}

extern "C" void kernel_launch(void* const* d_in, const int* in_sizes, int n_in,
                              void* d_out, int out_size, void* d_ws, size_t ws_size,
                              hipStream_t stream) {
    const float* x  = (const float*)d_in[0];
    const float* w1 = (const float*)d_in[1];
    const float* b1 = (const float*)d_in[2];
    const float* w2 = (const float*)d_in[3];
    float* out = (float*)d_out;

    // workspace: w1t (4 MB) | P (32 MB)  = 36 MB
    unsigned short* w1t = (unsigned short*)d_ws;
    float* P = (float*)((char*)d_ws + (4u << 20));

    convert_w1_kernel<<<512, 512, 0, stream>>>(w1, w1t);
    gemm1_mfma_kernel<<<512, 256, 0, stream>>>(x, w1t, P);
    reduce_gate_kernel<<<512, 512, 0, stream>>>(P, b1, w2, out);
}